// Round 5
// baseline (508.533 us; speedup 1.0000x reference)
//
#include <hip/hip_runtime.h>

// ---------------------------------------------------------------------------
// MultiHeadAttention (B=1, N=2925, D_MODEL=1536, 12 heads x 128) on gfx950.
// convert/transpose -> fused QKV bf16-MFMA GEMM -> RMSNorm+3D RoPE ->
// V transpose -> split-KV(x4) flash attention (32x32 MFMA, S^T orientation,
// swizzled LDS, exp2 softmax) -> combine+transpose -> O GEMM.
// ---------------------------------------------------------------------------

#define N_TOK 2925
#define DMODEL 1536
#define NHEAD 12
#define HDIM 128
#define VT_STRIDE 2944        // N_TOK padded to x64; pad MUST be zeroed (NaN hazard)
#define QPAD 2944             // q-row padding (23 tiles x 128)
#define NSPLIT 4

typedef __attribute__((ext_vector_type(8))) __bf16 bf16x8;
typedef __attribute__((ext_vector_type(4))) float floatx4;
typedef __attribute__((ext_vector_type(16))) float floatx16;

#define MFMA(a, b, c)   __builtin_amdgcn_mfma_f32_16x16x32_bf16((a), (b), (c), 0, 0, 0)
#define MFMA32(a, b, c) __builtin_amdgcn_mfma_f32_32x32x16_bf16((a), (b), (c), 0, 0, 0)

static __device__ __forceinline__ unsigned short f2bf(float f) {
    unsigned u = __builtin_bit_cast(unsigned, f);
    return (unsigned short)((u + 0x7fffu + ((u >> 16) & 1u)) >> 16);
}
static __device__ __forceinline__ float bf2f(unsigned short s) {
    unsigned u = ((unsigned)s) << 16;
    return __builtin_bit_cast(float, u);
}
// pack two fp32 into bf16x2 (truncation) with one v_perm_b32
static __device__ __forceinline__ unsigned packbf2(float a, float b) {
    return __builtin_amdgcn_perm(__builtin_bit_cast(unsigned, b),
                                 __builtin_bit_cast(unsigned, a), 0x07060302u);
}

// ---------------------------------------------------------------- convert x
__global__ __launch_bounds__(256) void k_convert_x(const float* __restrict__ x,
                                                   unsigned short* __restrict__ xb, int n) {
    int i = (blockIdx.x * 256 + threadIdx.x) * 4;
    if (i < n) {
        float4 v = *(const float4*)(x + i);
        uint2 o;
        o.x = (unsigned)f2bf(v.x) | ((unsigned)f2bf(v.y) << 16);
        o.y = (unsigned)f2bf(v.z) | ((unsigned)f2bf(v.w) << 16);
        *(uint2*)(xb + i) = o;
    }
}

// ---------------------------------------------- transpose W [k][n] -> Wt [n][k] bf16
__global__ __launch_bounds__(256) void k_transpose_w(const float* __restrict__ W0,
                                                     const float* __restrict__ W1,
                                                     const float* __restrict__ W2,
                                                     const float* __restrict__ W3,
                                                     unsigned short* __restrict__ Wt) {
    __shared__ float tile[32][33];
    const float* W = blockIdx.z == 0 ? W0 : blockIdx.z == 1 ? W1 : blockIdx.z == 2 ? W2 : W3;
    unsigned short* out = Wt + (size_t)blockIdx.z * DMODEL * DMODEL;
    int tx = threadIdx.x, ty = threadIdx.y;           // 32 x 8
    int bx = blockIdx.x * 32, by = blockIdx.y * 32;
#pragma unroll
    for (int i = 0; i < 4; i++)
        tile[ty + 8 * i][tx] = W[(size_t)(by + ty + 8 * i) * DMODEL + bx + tx];
    __syncthreads();
#pragma unroll
    for (int i = 0; i < 4; i++)
        out[(size_t)(bx + ty + 8 * i) * DMODEL + by + tx] = f2bf(tile[tx][ty + 8 * i]);
}

// ------------------------------------------------------------ bf16 MFMA GEMM
__global__ __launch_bounds__(256, 2) void k_gemm(const unsigned short* __restrict__ A,
                                                 const unsigned short* __restrict__ BtBase,
                                                 const float* __restrict__ b0,
                                                 const float* __restrict__ b1,
                                                 const float* __restrict__ b2,
                                                 float* __restrict__ Cbase, int M) {
    const int z = blockIdx.z;
    const unsigned short* Bt = BtBase + (size_t)z * DMODEL * DMODEL;
    const float* bias = (z == 0) ? b0 : (z == 1) ? b1 : b2;
    float* C = Cbase + (size_t)z * M * DMODEL;

    __shared__ unsigned short As[128 * 40];
    __shared__ unsigned short Bs[128 * 40];

    const int tid = threadIdx.x;
    const int wave = tid >> 6, lane = tid & 63, quad = lane >> 4, l16 = lane & 15;
    const int wr = wave >> 1, wc = wave & 1;
    const int m0 = blockIdx.y * 128, n0 = blockIdx.x * 128;

    floatx4 acc[4][4] = {};

    for (int k0 = 0; k0 < DMODEL; k0 += 32) {
#pragma unroll
        for (int c = 0; c < 2; c++) {
            int chunk = tid + 256 * c;
            int row = chunk >> 2, col = (chunk & 3) * 8;
            int gm = m0 + row;
            uint4 va = make_uint4(0, 0, 0, 0);
            if (gm < M) va = *(const uint4*)(A + (size_t)gm * DMODEL + k0 + col);
            *(uint4*)&As[row * 40 + col] = va;
            uint4 vb = *(const uint4*)(Bt + (size_t)(n0 + row) * DMODEL + k0 + col);
            *(uint4*)&Bs[row * 40 + col] = vb;
        }
        __syncthreads();

        bf16x8 af[4], bfm[4];
#pragma unroll
        for (int i = 0; i < 4; i++)
            af[i] = *(const bf16x8*)&As[(wr * 64 + i * 16 + l16) * 40 + quad * 8];
#pragma unroll
        for (int j = 0; j < 4; j++)
            bfm[j] = *(const bf16x8*)&Bs[(wc * 64 + j * 16 + l16) * 40 + quad * 8];
#pragma unroll
        for (int i = 0; i < 4; i++)
#pragma unroll
            for (int j = 0; j < 4; j++)
                acc[i][j] = MFMA(af[i], bfm[j], acc[i][j]);
        __syncthreads();
    }

#pragma unroll
    for (int j = 0; j < 4; j++) {
        int cg = n0 + wc * 64 + j * 16 + l16;
        float bv = bias[cg];
#pragma unroll
        for (int i = 0; i < 4; i++) {
            int rbase = m0 + wr * 64 + i * 16 + quad * 4;
#pragma unroll
            for (int r = 0; r < 4; r++) {
                int rg = rbase + r;
                if (rg < M) C[(size_t)rg * DMODEL + cg] = acc[i][j][r] + bv;
            }
        }
    }
}

// ---------------------------------- fused RMSNorm (full 1536) + 3D RoPE + pack
// q pre-scaled by (1/sqrt(HDIM))*log2(e)  -> softmax runs in exp2 domain.
__global__ __launch_bounds__(256) void k_norm_rope(const float* __restrict__ Qf,
                                                   const float* __restrict__ Kf,
                                                   const float* __restrict__ Vf,
                                                   const float* __restrict__ qsc,
                                                   const float* __restrict__ ksc,
                                                   const float* __restrict__ ft,
                                                   const float* __restrict__ fh,
                                                   const float* __restrict__ fw,
                                                   unsigned short* __restrict__ qb,
                                                   unsigned short* __restrict__ kb,
                                                   unsigned short* __restrict__ vb) {
    const int n = blockIdx.x;
    const int tid = threadIdx.x, wave = tid >> 6, lane = tid & 63;
    const int t_i = n / 225, rem = n % 225, h_i = rem / 15, w_i = rem % 15;
    const float att_scale = 0.08838834764831845f * 1.4426950408889634f;  // 1/sqrt(128)*log2e

    float2 qv[3], kv[3], vv[3];
    float sq = 0.f, sk = 0.f;
#pragma unroll
    for (int c = 0; c < 3; c++) {
        int p = tid + 256 * c;
        qv[c] = *(const float2*)(Qf + (size_t)n * DMODEL + 2 * p);
        kv[c] = *(const float2*)(Kf + (size_t)n * DMODEL + 2 * p);
        vv[c] = *(const float2*)(Vf + (size_t)n * DMODEL + 2 * p);
        sq += qv[c].x * qv[c].x + qv[c].y * qv[c].y;
        sk += kv[c].x * kv[c].x + kv[c].y * kv[c].y;
    }
#pragma unroll
    for (int off = 32; off >= 1; off >>= 1) {
        sq += __shfl_xor(sq, off, 64);
        sk += __shfl_xor(sk, off, 64);
    }
    __shared__ float red[2][4];
    if (lane == 0) { red[0][wave] = sq; red[1][wave] = sk; }
    __syncthreads();
    sq = red[0][0] + red[0][1] + red[0][2] + red[0][3];
    sk = red[1][0] + red[1][1] + red[1][2] + red[1][3];
    const float rq = rsqrtf(sq * (1.f / 1536.f) + 1e-6f) * att_scale;
    const float rk = rsqrtf(sk * (1.f / 1536.f) + 1e-6f);

#pragma unroll
    for (int c = 0; c < 3; c++) {
        int p = tid + 256 * c;
        int hd = p >> 6, pl = p & 63, dd = 2 * pl;
        float cs, sn;
        if (pl < 22)      { cs = ft[t_i * 44 + 2 * pl];        sn = ft[t_i * 44 + 2 * pl + 1]; }
        else if (pl < 43) { int pp = pl - 22; cs = fh[h_i * 42 + 2 * pp]; sn = fh[h_i * 42 + 2 * pp + 1]; }
        else              { int pp = pl - 43; cs = fw[w_i * 42 + 2 * pp]; sn = fw[w_i * 42 + 2 * pp + 1]; }
        int hidx = hd * 128 + dd;
        float q0 = qv[c].x * rq * qsc[hidx], q1 = qv[c].y * rq * qsc[hidx + 1];
        float k0 = kv[c].x * rk * ksc[hidx], k1 = kv[c].y * rk * ksc[hidx + 1];
        size_t o = ((size_t)hd * N_TOK + n) * HDIM + dd;
        unsigned qo = (unsigned)f2bf(q0 * cs - q1 * sn) | ((unsigned)f2bf(q0 * sn + q1 * cs) << 16);
        unsigned ko = (unsigned)f2bf(k0 * cs - k1 * sn) | ((unsigned)f2bf(k0 * sn + k1 * cs) << 16);
        unsigned vo = (unsigned)f2bf(vv[c].x) | ((unsigned)f2bf(vv[c].y) << 16);
        *(unsigned*)(qb + o) = qo;
        *(unsigned*)(kb + o) = ko;
        *(unsigned*)(vb + o) = vo;
    }
}

// ----------------- transpose V: [head][tok][128] -> [head][128][VT_STRIDE] bf16
// Pad columns [N_TOK, VT_STRIDE) are WRITTEN AS ZERO (recycled region NaN hazard).
__global__ __launch_bounds__(256) void k_transpose_v(const unsigned short* __restrict__ vbi,
                                                     unsigned short* __restrict__ vt) {
    __shared__ unsigned short tile[32][33];
    const int head = blockIdx.z;
    const int t0 = blockIdx.x * 32, d0 = blockIdx.y * 32;
    const int tx = threadIdx.x, ty = threadIdx.y;      // 32 x 8
#pragma unroll
    for (int i = 0; i < 4; i++) {
        int t = t0 + ty + 8 * i;
        tile[ty + 8 * i][tx] = (t < N_TOK) ? vbi[((size_t)head * N_TOK + t) * HDIM + d0 + tx] : 0;
    }
    __syncthreads();
    int t = t0 + tx;                                   // < VT_STRIDE always
#pragma unroll
    for (int i = 0; i < 4; i++)
        vt[((size_t)head * HDIM + d0 + ty + 8 * i) * VT_STRIDE + t] = tile[tx][ty + 8 * i];
}

// ------------------- split-KV(x4) flash attention, 32x32 MFMA, S^T orientation
// Block = (128 q-rows, head, split); 4 waves x 32 rows. KV tiles of 64.
// Per lane: one q-row (lane&31), half the k-range (lane>>5). LDS chunk-swizzle
// sw=(row>>3)&3 makes K/V/P frag reads conflict-free. exp2-domain softmax.
// Outputs un-normalized O^T (bf16) [split*12+head][d][QPAD] + m,l per row.
#define ATTN_TILE(MASKED, klen)                                               \
  {                                                                           \
    _Pragma("unroll")                                                         \
    for (int c = 0; c < 4; c++) {                                             \
      int ch = tid + 256 * c; int key = ch >> 4, kc = ch & 15;                \
      int gk = kb0 + key; if (gk > N_TOK - 1) gk = N_TOK - 1;                 \
      *(uint4*)&Ks[key * 136 + (kc ^ ((key >> 3) & 3)) * 8] =                 \
          *(const uint4*)(kh + (size_t)gk * HDIM + kc * 8);                   \
    }                                                                         \
    _Pragma("unroll")                                                         \
    for (int c = 0; c < 4; c++) {                                             \
      int ch = tid + 256 * c; int d = ch >> 3, vc = ch & 7;                   \
      *(uint4*)&Vs[d * 72 + (vc ^ ((d >> 3) & 3)) * 8] =                      \
          *(const uint4*)(vh + (size_t)d * VT_STRIDE + kb0 + vc * 8);         \
    }                                                                         \
    __syncthreads();                                                          \
    floatx16 sa0 = (floatx16)0.f, sa1 = (floatx16)0.f;                        \
    _Pragma("unroll")                                                         \
    for (int ks = 0; ks < 8; ks++) {                                          \
      int cc = ((h + 2 * ks) ^ swq) * 8;                                      \
      bf16x8 ak0 = *(const bf16x8*)&Ks[q31 * 136 + cc];                       \
      bf16x8 ak1 = *(const bf16x8*)&Ks[(q31 + 32) * 136 + cc];                \
      sa0 = MFMA32(ak0, aq[ks], sa0);                                         \
      sa1 = MFMA32(ak1, aq[ks], sa1);                                         \
    }                                                                         \
    float mnew = m_r;                                                         \
    _Pragma("unroll")                                                         \
    for (int r = 0; r < 16; r++) {                                            \
      float v0 = sa0[r], v1 = sa1[r];                                         \
      if (MASKED) {                                                           \
        int klo = (r & 3) + 8 * (r >> 2) + 4 * h;                             \
        if (klo >= (klen)) v0 = -1e30f;                                       \
        if (klo + 32 >= (klen)) v1 = -1e30f;                                  \
      }                                                                       \
      mnew = fmaxf(mnew, fmaxf(v0, v1));                                      \
    }                                                                         \
    mnew = fmaxf(mnew, __shfl_xor(mnew, 32, 64));                             \
    const float alpha = exp2f(m_r - mnew); m_r = mnew;                        \
    float rsum = 0.f;                                                         \
    _Pragma("unroll")                                                         \
    for (int mt = 0; mt < 2; mt++)                                            \
      _Pragma("unroll")                                                       \
      for (int g = 0; g < 4; g++) {                                           \
        float p[4];                                                           \
        _Pragma("unroll")                                                     \
        for (int j = 0; j < 4; j++) {                                         \
          int r = g * 4 + j;                                                  \
          float v = mt ? sa1[r] : sa0[r];                                     \
          if (MASKED) {                                                       \
            int kl = 32 * mt + (r & 3) + 8 * (r >> 2) + 4 * h;                \
            if (kl >= (klen)) v = -1e30f;                                     \
          }                                                                   \
          p[j] = exp2f(v - mnew);                                             \
        }                                                                     \
        rsum += (p[0] + p[1]) + (p[2] + p[3]);                                \
        uint2 pk;                                                             \
        pk.x = packbf2(p[0], p[1]);                                           \
        pk.y = packbf2(p[2], p[3]);                                           \
        *(uint2*)&ps[q31 * 72 + ((4 * mt + g) ^ swq) * 8 + 4 * h] = pk;       \
      }                                                                       \
    l_r = l_r * alpha + rsum + __shfl_xor(rsum, 32, 64);                      \
    if (__any(alpha != 1.f)) {                                                \
      _Pragma("unroll")                                                       \
      for (int mt = 0; mt < 4; mt++)                                          \
        _Pragma("unroll")                                                     \
        for (int r = 0; r < 16; r++) oacc[mt][r] *= alpha;                    \
    }                                                                         \
    _Pragma("unroll")                                                         \
    for (int ks = 0; ks < 4; ks++) {                                          \
      int cc = ((h + 2 * ks) ^ swq) * 8;                                      \
      bf16x8 bp = *(const bf16x8*)&ps[q31 * 72 + cc];                         \
      _Pragma("unroll")                                                       \
      for (int mt = 0; mt < 4; mt++) {                                        \
        bf16x8 av = *(const bf16x8*)&Vs[(mt * 32 + q31) * 72 + cc];           \
        oacc[mt] = MFMA32(av, bp, oacc[mt]);                                  \
      }                                                                       \
    }                                                                         \
    __syncthreads();                                                          \
  }

__global__ __launch_bounds__(256, 3) void k_attn_part(const unsigned short* __restrict__ qb,
                                                      const unsigned short* __restrict__ kb,
                                                      const unsigned short* __restrict__ vt,
                                                      unsigned short* __restrict__ Opart,
                                                      float* __restrict__ mbuf,
                                                      float* __restrict__ lbuf) {
    __shared__ unsigned short Ks[64 * 136];    // [key][d-chunks swizzled]  17.0KB
    __shared__ unsigned short Vs[128 * 72];    // [d][key-chunks swizzled]  18.0KB
    __shared__ unsigned short Ps[4][32 * 72];  // per-wave P [qrow][key]    18.0KB

    const int tid = threadIdx.x, wave = tid >> 6, lane = tid & 63;
    const int h = lane >> 5, q31 = lane & 31;
    const int head = blockIdx.y, z = blockIdx.z;
    const int kbeg = (z <= 2) ? z * 768 : 2240;
    const int kend = (z <= 1) ? (z + 1) * 768 : (z == 2 ? 2240 : N_TOK);
    const int q0 = blockIdx.x * 128 + wave * 32;
    const unsigned short* qh = qb + (size_t)head * N_TOK * HDIM;
    const unsigned short* kh = kb + (size_t)head * N_TOK * HDIM;
    const unsigned short* vh = vt + (size_t)head * HDIM * VT_STRIDE;
    unsigned short* ps = Ps[wave];
    const int swq = (q31 >> 3) & 3;

    // Q fragments (B-operand: n=q-row=lane&31, k=d=(lane>>5)*8+j per 16-k step)
    bf16x8 aq[8];
    {
        int qr = q0 + q31; if (qr > N_TOK - 1) qr = N_TOK - 1;
#pragma unroll
        for (int ks = 0; ks < 8; ks++)
            aq[ks] = *(const bf16x8*)&qh[(size_t)qr * HDIM + ks * 16 + h * 8];
    }

    floatx16 oacc[4] = {};
    float m_r = -1e30f, l_r = 0.f;

    int kb0 = kbeg;
    const int nfull = (kend - kbeg) >> 6;
    for (int t = 0; t < nfull; t++, kb0 += 64) ATTN_TILE(false, 64)
    if (kb0 < kend) { const int klen = kend - kb0; ATTN_TILE(true, klen) }

    // store un-normalized O^T (bf16) + m,l
    unsigned short* ob = Opart + (size_t)(z * NHEAD + head) * HDIM * QPAD;
#pragma unroll
    for (int mt = 0; mt < 4; mt++)
#pragma unroll
        for (int r = 0; r < 16; r++) {
            int d = mt * 32 + (r & 3) + 8 * (r >> 2) + 4 * h;
            ob[(size_t)d * QPAD + q0 + q31] = f2bf(oacc[mt][r]);
        }
    if (h == 0) {
        int mi = (z * NHEAD + head) * QPAD + q0 + q31;
        mbuf[mi] = m_r;
        lbuf[mi] = l_r;
    }
}

// --------------------- combine 4 KV splits (exp2 domain) + transpose to [tok][dm]
__global__ __launch_bounds__(256) void k_combine(const unsigned short* __restrict__ Opart,
                                                 const float* __restrict__ mbuf,
                                                 const float* __restrict__ lbuf,
                                                 unsigned short* __restrict__ ab) {
    __shared__ unsigned short Ts[64 * 136];
    const int tid = threadIdx.x, wave = tid >> 6, lane = tid & 63;
    const int head = blockIdx.y;
    const int t0 = blockIdx.x * 64;
    const int tok = t0 + lane;                 // < QPAD always

    float m[NSPLIT], l[NSPLIT], w[NSPLIT];
#pragma unroll
    for (int s = 0; s < NSPLIT; s++) {
        int mi = (s * NHEAD + head) * QPAD + tok;
        m[s] = mbuf[mi]; l[s] = lbuf[mi];
    }
    float mm = fmaxf(fmaxf(m[0], m[1]), fmaxf(m[2], m[3]));
    float den = 0.f;
#pragma unroll
    for (int s = 0; s < NSPLIT; s++) { w[s] = exp2f(m[s] - mm); den += l[s] * w[s]; }
    float inv = 1.f / den;
#pragma unroll
    for (int s = 0; s < NSPLIT; s++) w[s] *= inv;

#pragma unroll 4
    for (int dd = 0; dd < 32; dd++) {
        int d = wave * 32 + dd;
        float acc = 0.f;
#pragma unroll
        for (int s = 0; s < NSPLIT; s++)
            acc += bf2f(Opart[((size_t)(s * NHEAD + head) * HDIM + d) * QPAD + tok]) * w[s];
        Ts[lane * 136 + d] = f2bf(acc);
    }
    __syncthreads();

    int row = tid >> 2, ch = tid & 3;
    int tk = t0 + row;
    if (tk < N_TOK) {
#pragma unroll
        for (int i = 0; i < 4; i++) {
            int c = ch + 4 * i;
            *(uint4*)(ab + (size_t)tk * DMODEL + head * HDIM + c * 8) = *(uint4*)&Ts[row * 136 + c * 8];
        }
    }
}

// ---------------------------------------------------------------------------
extern "C" void kernel_launch(void* const* d_in, const int* in_sizes, int n_in,
                              void* d_out, int out_size, void* d_ws, size_t ws_size,
                              hipStream_t stream) {
    const float* x   = (const float*)d_in[0];
    const float* Wq  = (const float*)d_in[1];
    const float* bq  = (const float*)d_in[2];
    const float* Wk  = (const float*)d_in[3];
    const float* bk  = (const float*)d_in[4];
    const float* Wv  = (const float*)d_in[5];
    const float* bv  = (const float*)d_in[6];
    const float* Wo  = (const float*)d_in[7];
    const float* bo  = (const float*)d_in[8];
    const float* qsc = (const float*)d_in[9];
    const float* ksc = (const float*)d_in[10];
    const float* ft  = (const float*)d_in[11];
    const float* fh  = (const float*)d_in[12];
    const float* fw  = (const float*)d_in[13];

    char* ws = (char*)d_ws;
    unsigned short* xb   = (unsigned short*)ws; ws += (size_t)N_TOK * DMODEL * 2;          // 8,985,600
    unsigned short* Wt   = (unsigned short*)ws; ws += (size_t)4 * DMODEL * DMODEL * 2;     // 18,874,368
    char* qkvf_region    = ws;                  ws += (size_t)3 * N_TOK * DMODEL * 4;      // 53,913,600
    unsigned short* qkvb = (unsigned short*)ws; ws += (size_t)3 * N_TOK * DMODEL * 2;      // 26,956,800
    unsigned short* ab   = (unsigned short*)ws; ws += (size_t)N_TOK * DMODEL * 2;          // 8,985,600

    // Phase 1: qkvf_region holds fp32 QKV projections (53.9 MB).
    float* Qf = (float*)qkvf_region;
    float* Kf = Qf + (size_t)N_TOK * DMODEL;
    float* Vf = Qf + (size_t)2 * N_TOK * DMODEL;
    // Phase 2 (after k_norm_rope): Opart bf16 36.2MB | m/l 1.1MB | vt 9.0MB = 46.3MB.
    unsigned short* Opart = (unsigned short*)qkvf_region;
    float* mbuf = (float*)(qkvf_region + (size_t)NSPLIT * NHEAD * HDIM * QPAD * 2);
    float* lbuf = mbuf + (size_t)NSPLIT * NHEAD * QPAD;
    unsigned short* vtp = (unsigned short*)(lbuf + (size_t)NSPLIT * NHEAD * QPAD);

    unsigned short* qbp = qkvb;
    unsigned short* kbp = qkvb + (size_t)N_TOK * DMODEL;
    unsigned short* vbp = qkvb + (size_t)2 * N_TOK * DMODEL;

    const int nelem = N_TOK * DMODEL;
    k_convert_x<<<(nelem / 4 + 255) / 256, 256, 0, stream>>>(x, xb, nelem);
    k_transpose_w<<<dim3(48, 48, 4), dim3(32, 8), 0, stream>>>(Wq, Wk, Wv, Wo, Wt);
    k_gemm<<<dim3(12, 23, 3), 256, 0, stream>>>(xb, Wt, bq, bk, bv, Qf, N_TOK);
    k_norm_rope<<<N_TOK, 256, 0, stream>>>(Qf, Kf, Vf, qsc, ksc, ft, fh, fw, qbp, kbp, vbp);
    k_transpose_v<<<dim3(92, 4, NHEAD), dim3(32, 8), 0, stream>>>(vbp, vtp);
    k_attn_part<<<dim3(23, NHEAD, NSPLIT), 256, 0, stream>>>(qbp, kbp, vtp, Opart, mbuf, lbuf);
    k_combine<<<dim3(46, NHEAD), 256, 0, stream>>>(Opart, mbuf, lbuf, ab);
    k_gemm<<<dim3(12, 23, 1), 256, 0, stream>>>(ab, Wt + (size_t)3 * DMODEL * DMODEL,
                                                bo, bo, bo, (float*)d_out, N_TOK);
}

// Round 6
// 423.584 us; speedup vs baseline: 1.2005x; 1.2005x over previous
//
#include <hip/hip_runtime.h>

// ---------------------------------------------------------------------------
// MultiHeadAttention (B=1, N=2925, D_MODEL=1536, 12 heads x 128) on gfx950.
// convert/transpose -> fused QKV bf16-MFMA GEMM (global_load_lds staging) ->
// RMSNorm+3D RoPE (exp2-domain q-scale) -> V transpose -> split-KV flash
// attention (R4 structure, exp2 softmax) -> combine -> O GEMM.
// ---------------------------------------------------------------------------

#define N_TOK 2925
#define DMODEL 1536
#define NHEAD 12
#define HDIM 128
#define KSPLIT 1472           // split-KV boundary (23 tiles of 64)
#define VT_STRIDE 2944        // N_TOK padded to x64; pad MUST be zeroed (NaN hazard)

typedef __attribute__((ext_vector_type(8))) __bf16 bf16x8;
typedef __attribute__((ext_vector_type(4))) float floatx4;

#define MFMA(a, b, c) __builtin_amdgcn_mfma_f32_16x16x32_bf16((a), (b), (c), 0, 0, 0)

static __device__ __forceinline__ unsigned short f2bf(float f) {
    unsigned u = __builtin_bit_cast(unsigned, f);
    return (unsigned short)((u + 0x7fffu + ((u >> 16) & 1u)) >> 16);
}

// async global->LDS 16B/lane (emits global_load_lds_dwordx4).
// LDS dest MUST be wave-uniform-base + lane*16.
static __device__ __forceinline__ void gload_lds16(const unsigned short* g, unsigned short* l) {
    __builtin_amdgcn_global_load_lds((const __attribute__((address_space(1))) void*)g,
                                     (__attribute__((address_space(3))) void*)l, 16, 0, 0);
}

// ---------------------------------------------------------------- convert x
__global__ __launch_bounds__(256) void k_convert_x(const float* __restrict__ x,
                                                   unsigned short* __restrict__ xb, int n) {
    int i = (blockIdx.x * 256 + threadIdx.x) * 4;
    if (i < n) {
        float4 v = *(const float4*)(x + i);
        uint2 o;
        o.x = (unsigned)f2bf(v.x) | ((unsigned)f2bf(v.y) << 16);
        o.y = (unsigned)f2bf(v.z) | ((unsigned)f2bf(v.w) << 16);
        *(uint2*)(xb + i) = o;
    }
}

// ---------------------------------------------- transpose W [k][n] -> Wt [n][k] bf16
__global__ __launch_bounds__(256) void k_transpose_w(const float* __restrict__ W0,
                                                     const float* __restrict__ W1,
                                                     const float* __restrict__ W2,
                                                     const float* __restrict__ W3,
                                                     unsigned short* __restrict__ Wt) {
    __shared__ float tile[32][33];
    const float* W = blockIdx.z == 0 ? W0 : blockIdx.z == 1 ? W1 : blockIdx.z == 2 ? W2 : W3;
    unsigned short* out = Wt + (size_t)blockIdx.z * DMODEL * DMODEL;
    int tx = threadIdx.x, ty = threadIdx.y;           // 32 x 8
    int bx = blockIdx.x * 32, by = blockIdx.y * 32;
#pragma unroll
    for (int i = 0; i < 4; i++)
        tile[ty + 8 * i][tx] = W[(size_t)(by + ty + 8 * i) * DMODEL + bx + tx];
    __syncthreads();
#pragma unroll
    for (int i = 0; i < 4; i++)
        out[(size_t)(bx + ty + 8 * i) * DMODEL + by + tx] = f2bf(tile[tx][ty + 8 * i]);
}

// ------------------------------------------------------------ bf16 MFMA GEMM
// m97 structure: unpadded stride-32 LDS tiles staged via global_load_lds(16B).
__global__ __launch_bounds__(256, 2) void k_gemm(const unsigned short* __restrict__ A,
                                                 const unsigned short* __restrict__ BtBase,
                                                 const float* __restrict__ b0,
                                                 const float* __restrict__ b1,
                                                 const float* __restrict__ b2,
                                                 float* __restrict__ Cbase, int M) {
    const int z = blockIdx.z;
    const unsigned short* Bt = BtBase + (size_t)z * DMODEL * DMODEL;
    const float* bias = (z == 0) ? b0 : (z == 1) ? b1 : b2;
    float* C = Cbase + (size_t)z * M * DMODEL;

    __shared__ __align__(16) unsigned short As[128 * 32];   // [row][k], contiguous
    __shared__ __align__(16) unsigned short Bs[128 * 32];   // [n][k],   contiguous

    const int tid = threadIdx.x;
    const int wave = tid >> 6, lane = tid & 63, quad = lane >> 4, l16 = lane & 15;
    const int wr = wave >> 1, wc = wave & 1;
    const int m0 = blockIdx.y * 128, n0 = blockIdx.x * 128;

    // staging coords: thread covers row r4 (+64 on 2nd issue), 16B col chunk c4
    const int r4 = tid >> 2, c4 = (tid & 3) * 8;
    // NOTE: A rows m0+r4(+64) may exceed M (max 2943 > 2924): reads land in the
    // next ws region (no fault); garbage only reaches acc rows discarded by rg<M.

    floatx4 acc[4][4] = {};

    for (int k0 = 0; k0 < DMODEL; k0 += 32) {
        gload_lds16(A + (size_t)(m0 + r4) * DMODEL + k0 + c4,       &As[r4 * 32 + c4]);
        gload_lds16(A + (size_t)(m0 + r4 + 64) * DMODEL + k0 + c4,  &As[(r4 + 64) * 32 + c4]);
        gload_lds16(Bt + (size_t)(n0 + r4) * DMODEL + k0 + c4,      &Bs[r4 * 32 + c4]);
        gload_lds16(Bt + (size_t)(n0 + r4 + 64) * DMODEL + k0 + c4, &Bs[(r4 + 64) * 32 + c4]);
        __syncthreads();

        bf16x8 af[4], bfm[4];
#pragma unroll
        for (int i = 0; i < 4; i++)
            af[i] = *(const bf16x8*)&As[(wr * 64 + i * 16 + l16) * 32 + quad * 8];
#pragma unroll
        for (int j = 0; j < 4; j++)
            bfm[j] = *(const bf16x8*)&Bs[(wc * 64 + j * 16 + l16) * 32 + quad * 8];
#pragma unroll
        for (int i = 0; i < 4; i++)
#pragma unroll
            for (int j = 0; j < 4; j++)
                acc[i][j] = MFMA(af[i], bfm[j], acc[i][j]);
        __syncthreads();
    }

#pragma unroll
    for (int j = 0; j < 4; j++) {
        int cg = n0 + wc * 64 + j * 16 + l16;
        float bv = bias[cg];
#pragma unroll
        for (int i = 0; i < 4; i++) {
            int rbase = m0 + wr * 64 + i * 16 + quad * 4;
#pragma unroll
            for (int r = 0; r < 4; r++) {
                int rg = rbase + r;
                if (rg < M) C[(size_t)rg * DMODEL + cg] = acc[i][j][r] + bv;
            }
        }
    }
}

// ---------------------------------- fused RMSNorm (full 1536) + 3D RoPE + pack
// q pre-scaled by (1/sqrt(HDIM))*log2(e) -> softmax runs in exp2 domain.
__global__ __launch_bounds__(256) void k_norm_rope(const float* __restrict__ Qf,
                                                   const float* __restrict__ Kf,
                                                   const float* __restrict__ Vf,
                                                   const float* __restrict__ qsc,
                                                   const float* __restrict__ ksc,
                                                   const float* __restrict__ ft,
                                                   const float* __restrict__ fh,
                                                   const float* __restrict__ fw,
                                                   unsigned short* __restrict__ qb,
                                                   unsigned short* __restrict__ kb,
                                                   unsigned short* __restrict__ vb) {
    const int n = blockIdx.x;
    const int tid = threadIdx.x, wave = tid >> 6, lane = tid & 63;
    const int t_i = n / 225, rem = n % 225, h_i = rem / 15, w_i = rem % 15;
    const float att_scale = 0.08838834764831845f * 1.4426950408889634f;  // 1/sqrt(128)*log2e

    float2 qv[3], kv[3], vv[3];
    float sq = 0.f, sk = 0.f;
#pragma unroll
    for (int c = 0; c < 3; c++) {
        int p = tid + 256 * c;
        qv[c] = *(const float2*)(Qf + (size_t)n * DMODEL + 2 * p);
        kv[c] = *(const float2*)(Kf + (size_t)n * DMODEL + 2 * p);
        vv[c] = *(const float2*)(Vf + (size_t)n * DMODEL + 2 * p);
        sq += qv[c].x * qv[c].x + qv[c].y * qv[c].y;
        sk += kv[c].x * kv[c].x + kv[c].y * kv[c].y;
    }
#pragma unroll
    for (int off = 32; off >= 1; off >>= 1) {
        sq += __shfl_xor(sq, off, 64);
        sk += __shfl_xor(sk, off, 64);
    }
    __shared__ float red[2][4];
    if (lane == 0) { red[0][wave] = sq; red[1][wave] = sk; }
    __syncthreads();
    sq = red[0][0] + red[0][1] + red[0][2] + red[0][3];
    sk = red[1][0] + red[1][1] + red[1][2] + red[1][3];
    const float rq = rsqrtf(sq * (1.f / 1536.f) + 1e-6f) * att_scale;
    const float rk = rsqrtf(sk * (1.f / 1536.f) + 1e-6f);

#pragma unroll
    for (int c = 0; c < 3; c++) {
        int p = tid + 256 * c;
        int hd = p >> 6, pl = p & 63, dd = 2 * pl;
        float cs, sn;
        if (pl < 22)      { cs = ft[t_i * 44 + 2 * pl];        sn = ft[t_i * 44 + 2 * pl + 1]; }
        else if (pl < 43) { int pp = pl - 22; cs = fh[h_i * 42 + 2 * pp]; sn = fh[h_i * 42 + 2 * pp + 1]; }
        else              { int pp = pl - 43; cs = fw[w_i * 42 + 2 * pp]; sn = fw[w_i * 42 + 2 * pp + 1]; }
        int hidx = hd * 128 + dd;
        float q0 = qv[c].x * rq * qsc[hidx], q1 = qv[c].y * rq * qsc[hidx + 1];
        float k0 = kv[c].x * rk * ksc[hidx], k1 = kv[c].y * rk * ksc[hidx + 1];
        size_t o = ((size_t)hd * N_TOK + n) * HDIM + dd;
        unsigned qo = (unsigned)f2bf(q0 * cs - q1 * sn) | ((unsigned)f2bf(q0 * sn + q1 * cs) << 16);
        unsigned ko = (unsigned)f2bf(k0 * cs - k1 * sn) | ((unsigned)f2bf(k0 * sn + k1 * cs) << 16);
        unsigned vo = (unsigned)f2bf(vv[c].x) | ((unsigned)f2bf(vv[c].y) << 16);
        *(unsigned*)(qb + o) = qo;
        *(unsigned*)(kb + o) = ko;
        *(unsigned*)(vb + o) = vo;
    }
}

// ----------------- transpose V: [head][tok][128] -> [head][128][VT_STRIDE] bf16
// Pad columns [N_TOK, VT_STRIDE) are WRITTEN AS ZERO (recycled region NaN hazard).
__global__ __launch_bounds__(256) void k_transpose_v(const unsigned short* __restrict__ vbi,
                                                     unsigned short* __restrict__ vt) {
    __shared__ unsigned short tile[32][33];
    const int head = blockIdx.z;
    const int t0 = blockIdx.x * 32, d0 = blockIdx.y * 32;
    const int tx = threadIdx.x, ty = threadIdx.y;      // 32 x 8
#pragma unroll
    for (int i = 0; i < 4; i++) {
        int t = t0 + ty + 8 * i;
        tile[ty + 8 * i][tx] = (t < N_TOK) ? vbi[((size_t)head * N_TOK + t) * HDIM + d0 + tx] : 0;
    }
    __syncthreads();
    int t = t0 + tx;                                   // < VT_STRIDE always
#pragma unroll
    for (int i = 0; i < 4; i++)
        vt[((size_t)head * HDIM + d0 + ty + 8 * i) * VT_STRIDE + t] = tile[tx][ty + 8 * i];
}

// ------------------------- split-KV flash attention, K/V^T LDS-staged (R4)
// Block = (q-tile 64 rows, head, split). 4 waves x 16 rows each. KV tiles of 64.
// exp2-domain softmax (log2e folded into q).
__global__ __launch_bounds__(256, 3) void k_attn_part(const unsigned short* __restrict__ qb,
                                                      const unsigned short* __restrict__ kb,
                                                      const unsigned short* __restrict__ vt,
                                                      float* __restrict__ Opart,
                                                      float* __restrict__ mbuf,
                                                      float* __restrict__ lbuf) {
    __shared__ unsigned short Ks[64 * 136];   // [key][d]   stride 68 dwords
    __shared__ unsigned short Vs[128 * 72];   // [d][key]   stride 36 dwords
    __shared__ unsigned short Ps[4][16 * 72]; // per-wave P [qrow][key]

    const int tid = threadIdx.x, wave = tid >> 6, lane = tid & 63;
    const int quad = lane >> 4, l16 = lane & 15;
    const int head = blockIdx.y, z = blockIdx.z;
    const int q0 = blockIdx.x * 64 + wave * 16;
    const unsigned short* qh = qb + (size_t)head * N_TOK * HDIM;
    const unsigned short* kh = kb + (size_t)head * N_TOK * HDIM;
    const unsigned short* vh = vt + (size_t)head * HDIM * VT_STRIDE;
    unsigned short* ps = Ps[wave];

    const int kbeg = z ? KSPLIT : 0;
    const int kend = z ? N_TOK : KSPLIT;

    // Q fragments (A-layout: lane row l16, k = ks*32+quad*8..+7), loaded once
    bf16x8 aq[4];
    {
        int qrow = q0 + l16;
        if (qrow < N_TOK) {
#pragma unroll
            for (int ks = 0; ks < 4; ks++)
                aq[ks] = *(const bf16x8*)&qh[(size_t)qrow * HDIM + ks * 32 + quad * 8];
        } else {
#pragma unroll
            for (int ks = 0; ks < 4; ks++) aq[ks] = (bf16x8)(__bf16)0.0f;
        }
    }

    floatx4 oacc[8] = {};
    float m_r[4] = {-1e30f, -1e30f, -1e30f, -1e30f};
    float l_r[4] = {0.f, 0.f, 0.f, 0.f};

    for (int kb0 = kbeg; kb0 < kend; kb0 += 64) {
        // ---- stage K tile (64 x 128) and V^T tile (128 x 64), vector copies
#pragma unroll
        for (int c = 0; c < 4; c++) {
            int chunk = tid + 256 * c;                 // 0..1023
            int row = chunk >> 4, col = (chunk & 15) * 8;
            int gk = kb0 + row; if (gk >= N_TOK) gk = N_TOK - 1;   // clamp; masked later
            *(uint4*)&Ks[row * 136 + col] = *(const uint4*)(kh + (size_t)gk * HDIM + col);
        }
#pragma unroll
        for (int c = 0; c < 4; c++) {
            int chunk = tid + 256 * c;                 // 0..1023
            int d = chunk >> 3, col = (chunk & 7) * 8;
            *(uint4*)&Vs[d * 72 + col] = *(const uint4*)(vh + (size_t)d * VT_STRIDE + kb0 + col);
        }
        __syncthreads();

        // ---- S = Q K^T for this wave's 16 rows x 64 keys
        floatx4 sa[4] = {};
#pragma unroll
        for (int j = 0; j < 4; j++) {
            bf16x8 bkf[4];
#pragma unroll
            for (int ks = 0; ks < 4; ks++)
                bkf[ks] = *(const bf16x8*)&Ks[(j * 16 + l16) * 136 + ks * 32 + quad * 8];
#pragma unroll
            for (int ks = 0; ks < 4; ks++)
                sa[j] = MFMA(aq[ks], bkf[ks], sa[j]);
        }

        // ---- online softmax (exp2 domain, scale pre-folded into q)
        bool valid[4];
#pragma unroll
        for (int j = 0; j < 4; j++) valid[j] = (kb0 + j * 16 + l16) < kend;

        float alpha[4];
#pragma unroll
        for (int r = 0; r < 4; r++) {
            float x = -1e30f;
#pragma unroll
            for (int j = 0; j < 4; j++) x = fmaxf(x, valid[j] ? sa[j][r] : -1e30f);
#pragma unroll
            for (int off = 8; off >= 1; off >>= 1) x = fmaxf(x, __shfl_xor(x, off, 16));
            float mnew = fmaxf(m_r[r], x);
            alpha[r] = exp2f(m_r[r] - mnew);
            m_r[r] = mnew;
        }
        float rsum[4] = {0.f, 0.f, 0.f, 0.f};
#pragma unroll
        for (int j = 0; j < 4; j++)
#pragma unroll
            for (int r = 0; r < 4; r++) {
                float p = valid[j] ? exp2f(sa[j][r] - m_r[r]) : 0.f;
                rsum[r] += p;
                ps[(quad * 4 + r) * 72 + j * 16 + l16] = f2bf(p);
            }
#pragma unroll
        for (int r = 0; r < 4; r++) {
            float s = rsum[r];
#pragma unroll
            for (int off = 8; off >= 1; off >>= 1) s += __shfl_xor(s, off, 16);
            l_r[r] = l_r[r] * alpha[r] + s;
        }
#pragma unroll
        for (int jd = 0; jd < 8; jd++)
#pragma unroll
            for (int r = 0; r < 4; r++) oacc[jd][r] *= alpha[r];

        // ---- O += P V  (P from per-wave LDS; V^T frags from LDS)
#pragma unroll
        for (int ks = 0; ks < 2; ks++) {
            bf16x8 ap = *(const bf16x8*)&ps[l16 * 72 + ks * 32 + quad * 8];
#pragma unroll
            for (int jd = 0; jd < 8; jd++) {
                bf16x8 bvf = *(const bf16x8*)&Vs[(jd * 16 + l16) * 72 + ks * 32 + quad * 8];
                oacc[jd] = MFMA(ap, bvf, oacc[jd]);
            }
        }
        __syncthreads();
    }

    // ---- store un-normalized O + (m,l)
#pragma unroll
    for (int r = 0; r < 4; r++) {
        int rg = q0 + quad * 4 + r;
        if (rg < N_TOK) {
            size_t rbase = ((size_t)(z * NHEAD + head) * N_TOK + rg) * HDIM;
#pragma unroll
            for (int jd = 0; jd < 8; jd++)
                Opart[rbase + jd * 16 + l16] = oacc[jd][r];
            if (l16 == 0) {
                int mi = (z * NHEAD + head) * N_TOK + rg;
                mbuf[mi] = m_r[r];
                lbuf[mi] = l_r[r];
            }
        }
    }
}

// ----------------------------------------------- combine the two KV splits
__global__ __launch_bounds__(256) void k_combine(const float* __restrict__ Opart,
                                                 const float* __restrict__ mbuf,
                                                 const float* __restrict__ lbuf,
                                                 unsigned short* __restrict__ ab) {
    const int R = NHEAD * N_TOK;
    int r = blockIdx.x * 8 + (threadIdx.x >> 5);
    if (r >= R) return;
    int l32 = threadIdx.x & 31;
    float m0 = mbuf[r], m1 = mbuf[R + r];
    float l0 = lbuf[r], l1 = lbuf[R + r];
    float m = fmaxf(m0, m1);
    float w0 = exp2f(m0 - m), w1 = exp2f(m1 - m);
    float inv = 1.f / (l0 * w0 + l1 * w1);
    w0 *= inv; w1 *= inv;
    float4 a = *(const float4*)&Opart[(size_t)r * HDIM + l32 * 4];
    float4 b = *(const float4*)&Opart[((size_t)R + r) * HDIM + l32 * 4];
    int head = r / N_TOK, tok = r % N_TOK;
    unsigned short* o = ab + (size_t)tok * DMODEL + head * HDIM + l32 * 4;
    uint2 pk;
    pk.x = (unsigned)f2bf(a.x * w0 + b.x * w1) | ((unsigned)f2bf(a.y * w0 + b.y * w1) << 16);
    pk.y = (unsigned)f2bf(a.z * w0 + b.z * w1) | ((unsigned)f2bf(a.w * w0 + b.w * w1) << 16);
    *(uint2*)o = pk;
}

// ---------------------------------------------------------------------------
extern "C" void kernel_launch(void* const* d_in, const int* in_sizes, int n_in,
                              void* d_out, int out_size, void* d_ws, size_t ws_size,
                              hipStream_t stream) {
    const float* x   = (const float*)d_in[0];
    const float* Wq  = (const float*)d_in[1];
    const float* bq  = (const float*)d_in[2];
    const float* Wk  = (const float*)d_in[3];
    const float* bk  = (const float*)d_in[4];
    const float* Wv  = (const float*)d_in[5];
    const float* bv  = (const float*)d_in[6];
    const float* Wo  = (const float*)d_in[7];
    const float* bo  = (const float*)d_in[8];
    const float* qsc = (const float*)d_in[9];
    const float* ksc = (const float*)d_in[10];
    const float* ft  = (const float*)d_in[11];
    const float* fh  = (const float*)d_in[12];
    const float* fw  = (const float*)d_in[13];

    // Layout note: ab sits BEFORE the fp32 region so the O-GEMM's A-tile
    // over-reads (rows 2925..2943) land inside d_ws, never past its end.
    char* ws = (char*)d_ws;
    unsigned short* xb   = (unsigned short*)ws; ws += (size_t)N_TOK * DMODEL * 2;          // 8,985,600
    unsigned short* Wt   = (unsigned short*)ws; ws += (size_t)4 * DMODEL * DMODEL * 2;     // 18,874,368
    unsigned short* ab   = (unsigned short*)ws; ws += (size_t)N_TOK * DMODEL * 2;          // 8,985,600
    char* qkvf_region    = ws;                  ws += (size_t)3 * N_TOK * DMODEL * 4;      // 53,913,600
    unsigned short* qkvb = (unsigned short*)ws; ws += (size_t)3 * N_TOK * DMODEL * 2;      // 26,956,800

    // Phase 1: qkvf_region holds fp32 QKV projections (53.9 MB).
    float* Qf = (float*)qkvf_region;
    float* Kf = Qf + (size_t)N_TOK * DMODEL;
    float* Vf = Qf + (size_t)2 * N_TOK * DMODEL;
    // Phase 2 (after k_norm_rope): Opart 35.9MB | m/l 0.56MB | vt 9.04MB = 45.5MB.
    float* Opart = (float*)qkvf_region;
    float* mbuf  = Opart + (size_t)2 * NHEAD * N_TOK * HDIM;
    float* lbuf  = mbuf + (size_t)2 * NHEAD * N_TOK;
    unsigned short* vtp = (unsigned short*)(lbuf + (size_t)2 * NHEAD * N_TOK);

    unsigned short* qbp = qkvb;
    unsigned short* kbp = qkvb + (size_t)N_TOK * DMODEL;
    unsigned short* vbp = qkvb + (size_t)2 * N_TOK * DMODEL;

    const int nelem = N_TOK * DMODEL;
    k_convert_x<<<(nelem / 4 + 255) / 256, 256, 0, stream>>>(x, xb, nelem);
    k_transpose_w<<<dim3(48, 48, 4), dim3(32, 8), 0, stream>>>(Wq, Wk, Wv, Wo, Wt);
    k_gemm<<<dim3(12, 23, 3), 256, 0, stream>>>(xb, Wt, bq, bk, bv, Qf, N_TOK);
    k_norm_rope<<<N_TOK, 256, 0, stream>>>(Qf, Kf, Vf, qsc, ksc, ft, fh, fw, qbp, kbp, vbp);
    k_transpose_v<<<dim3(92, 4, NHEAD), dim3(32, 8), 0, stream>>>(vbp, vtp);
    k_attn_part<<<dim3(46, NHEAD, 2), 256, 0, stream>>>(qbp, kbp, vtp, Opart, mbuf, lbuf);
    k_combine<<<(NHEAD * N_TOK + 7) / 8, 256, 0, stream>>>(Opart, mbuf, lbuf, ab);
    k_gemm<<<dim3(12, 23, 1), 256, 0, stream>>>(ab, Wt + (size_t)3 * DMODEL * DMODEL,
                                                bo, bo, bo, (float*)d_out, N_TOK);
}